// Round 7
// baseline (17511.462 us; speedup 1.0000x reference)
//
#include <hip/hip_runtime.h>

#define T_STEPS 100
#define B_SIZE  512
#define I_SIZE  700
#define H_SIZE  512
#define O_SIZE  20

#define ALPHA 0.8187307530779818f   // exp(-0.001/0.005) rounded to f32
#define BETA  0.9048374180359595f   // exp(-0.001/0.010) rounded to f32
#define REG   1e-7

// ---------------- zero the spike-count accumulators ----------------
__global__ void init_counts_kernel(int* __restrict__ g) {
    int tid = threadIdx.x;
    if (tid < 2 * H_SIZE) g[tid] = 0;
}

// ---------------- main SNN kernel: one block per batch element ----------------
// Engine model of the numpy reference:
//   - einsum dots (cur0, h2): numpy's float_sum_of_products_contig_two =
//     4-lane SSE: lane l accumulates k ≡ l (mod 4) ascending; horizontal
//     reduce (hadd twice) = (L0+L1)+(L2+L3). K=700,512 both %4==0 (no tail).
//   - matmul dots (cur1 via BLAS sgemm): ascending sequential per element
//     (k-blocking continues the same chain for binary A => order-equivalent).
//     Two matmul RESULTS (W1 term, Wrec term) added as f32.
//   - binary spikes => products exact; only add grouping matters.
//   - states / readout filter: rn mul then rn add (numpy scalar semantics).
__global__ __launch_bounds__(512, 1)
void snn_einsum_kernel(const float* __restrict__ spikes,   // (B,T,I)
                       const float* __restrict__ W0,       // (H,I)
                       const float* __restrict__ W1,       // (H,H)
                       const float* __restrict__ Wrec,     // (H,H)
                       const float* __restrict__ Wout,     // (O,H)
                       const float* __restrict__ bout,     // (O)
                       float* __restrict__ out,            // (B,T+1,O)
                       int* __restrict__ gcnt0,            // (H)
                       int* __restrict__ gcnt1)            // (H)
{
    const int tid = threadIdx.x;     // h index
    const int b   = blockIdx.x;

    __shared__ float sIn[I_SIZE];    // input spike flags (this step)
    __shared__ float sS0[H_SIZE];    // layer-0 spikes (this step)
    __shared__ float sA[H_SIZE];     // layer-1 spikes ping
    __shared__ float sB[H_SIZE];     // layer-1 spikes pong

    float m0 = 0.f, s0 = 0.f, m1 = 0.f, s1 = 0.f;
    int   c0 = 0, c1 = 0;

    float flt = 0.f, outv = 0.f, bo = 0.f;
    if (tid < O_SIZE) {
        bo = bout[tid];
        out[((size_t)b * (T_STEPS + 1)) * O_SIZE + tid] = bo;   // t = 0 row
    }

    sA[tid] = 0.f;                   // spk1 at t=-1 is zero
    float* sp1Prev = sA;
    float* sp1Cur  = sB;

    const float* srow = spikes + (size_t)b * T_STEPS * I_SIZE;
    const float* W0r  = W0   + (size_t)tid * I_SIZE;   // this thread's row
    const float* W1r  = W1   + (size_t)tid * H_SIZE;
    const float* Wrr  = Wrec + (size_t)tid * H_SIZE;

    for (int t = 0; t < T_STEPS; ++t) {
        float f0 = ((m0 - 1.0f) > 0.0f) ? 1.0f : 0.0f;
        float f1 = ((m1 - 1.0f) > 0.0f) ? 1.0f : 0.0f;

        sIn[tid] = srow[t * I_SIZE + tid];
        if (tid < I_SIZE - H_SIZE)
            sIn[H_SIZE + tid] = srow[t * I_SIZE + H_SIZE + tid];
        sS0[tid]    = f0;
        sp1Cur[tid] = f1;
        __syncthreads();

        // ---- cur0 (einsum engine): mod-4 lanes, (L0+L1)+(L2+L3) ----
        float e0 = 0.f, e1 = 0.f, e2 = 0.f, e3 = 0.f;
        for (int i = 0; i < I_SIZE; i += 4) {
            if (sIn[i + 0] != 0.f) e0 = __fadd_rn(e0, W0r[i + 0]);
            if (sIn[i + 1] != 0.f) e1 = __fadd_rn(e1, W0r[i + 1]);
            if (sIn[i + 2] != 0.f) e2 = __fadd_rn(e2, W0r[i + 2]);
            if (sIn[i + 3] != 0.f) e3 = __fadd_rn(e3, W0r[i + 3]);
        }
        float cur0 = __fadd_rn(__fadd_rn(e0, e1), __fadd_rn(e2, e3));

        // ---- cur1 (BLAS engine): ascending sequential, two results added ----
        float a1 = 0.f;
        for (int j = 0; j < H_SIZE; ++j)
            if (sS0[j] != 0.f) a1 = __fadd_rn(a1, W1r[j]);
        float ar = 0.f;
        for (int j = 0; j < H_SIZE; ++j)
            if (sp1Prev[j] != 0.f) ar = __fadd_rn(ar, Wrr[j]);
        float cur1 = __fadd_rn(a1, ar);

        // ---- LIF updates: rn mul-then-add, reference order ----
        float ns0 = __fadd_rn(__fmul_rn(ALPHA, s0), cur0);
        float nm0 = __fmul_rn(__fadd_rn(__fmul_rn(BETA, m0), s0), 1.0f - f0);
        float ns1 = __fadd_rn(__fmul_rn(ALPHA, s1), cur1);
        float nm1 = __fmul_rn(__fadd_rn(__fmul_rn(BETA, m1), s1), 1.0f - f1);
        s0 = ns0; m0 = nm0; s1 = ns1; m1 = nm1;
        c0 += (f0 != 0.f); c1 += (f1 != 0.f);

        // ---- readout: h2 (einsum engine, mod-4), rn filter ----
        if (tid < O_SIZE) {
            const float* Wor = Wout + (size_t)tid * H_SIZE;
            float g0 = 0.f, g1 = 0.f, g2 = 0.f, g3 = 0.f;
            for (int j = 0; j < H_SIZE; j += 4) {
                if (sp1Cur[j + 0] != 0.f) g0 = __fadd_rn(g0, Wor[j + 0]);
                if (sp1Cur[j + 1] != 0.f) g1 = __fadd_rn(g1, Wor[j + 1]);
                if (sp1Cur[j + 2] != 0.f) g2 = __fadd_rn(g2, Wor[j + 2]);
                if (sp1Cur[j + 3] != 0.f) g3 = __fadd_rn(g3, Wor[j + 3]);
            }
            float h2 = __fadd_rn(__fadd_rn(g0, g1), __fadd_rn(g2, g3));

            float nflt = __fadd_rn(__fmul_rn(ALPHA, flt), h2);
            float nout = __fadd_rn(__fmul_rn(BETA, outv), flt);  // OLD flt
            flt = nflt; outv = nout;
            out[((size_t)b * (T_STEPS + 1) + (t + 1)) * O_SIZE + tid] = __fadd_rn(nout, bo);
        }

        __syncthreads();   // all reads of flags done before next-iter overwrite
        float* tmp = sp1Prev; sp1Prev = sp1Cur; sp1Cur = tmp;
    }

    atomicAdd(&gcnt0[tid], c0);
    atomicAdd(&gcnt1[tid], c1);
}

// ---------------- reg loss ----------------
__global__ void reg_kernel(const int* __restrict__ g0,
                           const int* __restrict__ g1,
                           float* __restrict__ out_reg) {
    int tid = threadIdx.x;     // 512 threads
    double v0 = (double)g0[tid], v1 = (double)g1[tid];
    double tot = v0 + v1;
    double sq  = v0 * v0 + v1 * v1;
    for (int off = 32; off; off >>= 1) {
        tot += __shfl_down(tot, off, 64);
        sq  += __shfl_down(sq,  off, 64);
    }
    __shared__ double stot[8], ssq[8];
    if ((tid & 63) == 0) { stot[tid >> 6] = tot; ssq[tid >> 6] = sq; }
    __syncthreads();
    if (tid == 0) {
        double Tt = 0.0, Sq = 0.0;
        for (int w = 0; w < 8; ++w) { Tt += stot[w]; Sq += ssq[w]; }
        // l1 terms: REG * (tot / (T*B*H));  l2 terms: REG * (sq / H)
        double reg = REG * (Tt / 26214400.0 + Sq / 512.0);
        *out_reg = (float)reg;
    }
}

extern "C" void kernel_launch(void* const* d_in, const int* in_sizes, int n_in,
                              void* d_out, int out_size, void* d_ws, size_t ws_size,
                              hipStream_t stream) {
    const float* spikes = (const float*)d_in[0];   // (512,100,700)
    const float* W0     = (const float*)d_in[1];   // (512,700)
    const float* W1     = (const float*)d_in[2];   // (512,512)
    const float* Wrec   = (const float*)d_in[3];   // (512,512)
    const float* Wout   = (const float*)d_in[4];   // (20,512)
    const float* bout   = (const float*)d_in[5];   // (20,)
    float* out = (float*)d_out;

    int* gcnt0 = (int*)d_ws;           // 512 ints
    int* gcnt1 = gcnt0 + H_SIZE;       // 512 ints  (4 KB total)

    init_counts_kernel<<<1, 1024, 0, stream>>>(gcnt0);

    snn_einsum_kernel<<<B_SIZE, H_SIZE, 0, stream>>>(spikes, W0, W1, Wrec, Wout,
                                                     bout, out, gcnt0, gcnt1);

    reg_kernel<<<1, H_SIZE, 0, stream>>>(gcnt0, gcnt1,
                                         out + (size_t)B_SIZE * (T_STEPS + 1) * O_SIZE);
}

// Round 8
// 2737.638 us; speedup vs baseline: 6.3966x; 6.3966x over previous
//
#include <hip/hip_runtime.h>

#define T_STEPS 100
#define B_SIZE  512
#define I_SIZE  700
#define H_SIZE  512
#define O_SIZE  20

#define ALPHA 0.8187307530779818f   // exp(-0.001/0.005) rounded to f32
#define BETA  0.9048374180359595f   // exp(-0.001/0.010) rounded to f32
#define REG   1e-7

// ---------------- transpose: out[c*R + r] = in[r*C + c] ----------------
__global__ void transpose_kernel(const float* __restrict__ in,
                                 float* __restrict__ out, int R, int C) {
    int idx = blockIdx.x * blockDim.x + threadIdx.x;
    if (idx < R * C) {
        int r = idx / C, c = idx % C;
        out[c * R + r] = in[r * C + c];
    }
}

// ---------------- zero the spike-count accumulators ----------------
__global__ void init_counts_kernel(int* __restrict__ g) {
    int tid = threadIdx.x;
    if (tid < 2 * H_SIZE) g[tid] = 0;
}

// ---------------- main SNN kernel: one block per batch element ----------------
// Sparse-compaction version of the bitwise-verified R7 engine model:
//   - active indices compacted per step via order-preserving ballot scan
//     (ascending index order within each list, guaranteed);
//   - einsum dots (cur0, h2): 4 accumulators by idx&3 (uniform switch),
//     combined (L0+L1)+(L2+L3) — identical grouping to numpy's SSE loop;
//   - BLAS dots (a1, ar): ascending sequential chains; cur1 = a1 + ar;
//   - states / filter: rn mul-then-add, reference operation order.
// All sums visit the same terms in the same order with the same grouping as
// the passing dense kernel => bitwise identical results.
__global__ __launch_bounds__(512, 1)
void snn_sparse_kernel(const float* __restrict__ spikes,   // (B,T,I)
                       const float* __restrict__ W0T,      // (I,H)
                       const float* __restrict__ W1T,      // (H,H)
                       const float* __restrict__ WrecT,    // (H,H)
                       const float* __restrict__ WoutT,    // (H,O)
                       const float* __restrict__ bout,     // (O)
                       float* __restrict__ out,            // (B,T+1,O)
                       int* __restrict__ gcnt0,            // (H)
                       int* __restrict__ gcnt1)            // (H)
{
    const int tid  = threadIdx.x;          // h index
    const int b    = blockIdx.x;
    const int lane = tid & 63;
    const int wave = tid >> 6;
    const unsigned long long lt = (1ULL << lane) - 1ULL;

    __shared__ int inIdx[I_SIZE];          // active input indices (ascending)
    __shared__ int l0Idx[H_SIZE];          // active layer-0 spikes (ascending)
    __shared__ int l1A[H_SIZE];            // layer-1 spike lists, ping/pong
    __shared__ int l1B[H_SIZE];
    __shared__ int waveCnt[4][8];
    __shared__ int grpOff[4][9];           // [group][wave], [.][8] = total

    float m0 = 0.f, s0 = 0.f, m1 = 0.f, s1 = 0.f;
    int   c0 = 0, c1 = 0;

    float flt = 0.f, outv = 0.f, bo = 0.f;
    if (tid < O_SIZE) {
        bo = bout[tid];
        out[((size_t)b * (T_STEPS + 1)) * O_SIZE + tid] = bo;   // t = 0 row
    }

    int* l1Prev = l1A;
    int* l1Cur  = l1B;
    int  n1Prev = 0;

    const float* srow = spikes + (size_t)b * T_STEPS * I_SIZE;

    for (int t = 0; t < T_STEPS; ++t) {
        // ---- per-thread flags ----
        float spA = srow[t * I_SIZE + tid];
        int   e2  = 512 + tid;
        float spB = (e2 < I_SIZE) ? srow[t * I_SIZE + e2] : 0.f;
        int f_inA = (spA != 0.f);
        int f_inB = (spB != 0.f);
        int f0    = ((m0 - 1.0f) > 0.0f);
        int f1    = ((m1 - 1.0f) > 0.0f);

        unsigned long long mAm = __ballot(f_inA);
        unsigned long long mBm = __ballot(f_inB);
        unsigned long long m0m = __ballot(f0);
        unsigned long long m1m = __ballot(f1);
        if (lane == 0) {
            waveCnt[0][wave] = __popcll(mAm);
            waveCnt[1][wave] = __popcll(mBm);
            waveCnt[2][wave] = __popcll(m0m);
            waveCnt[3][wave] = __popcll(m1m);
        }
        __syncthreads();                                   // sync #1

        if (tid == 0) {                 // input groups 0,1 share one list
            int acc = 0;
            for (int w = 0; w < 8; ++w) { grpOff[0][w] = acc; acc += waveCnt[0][w]; }
            for (int w = 0; w < 8; ++w) { grpOff[1][w] = acc; acc += waveCnt[1][w]; }
            grpOff[1][8] = acc;
        } else if (tid == 64) {
            int acc = 0;
            for (int w = 0; w < 8; ++w) { grpOff[2][w] = acc; acc += waveCnt[2][w]; }
            grpOff[2][8] = acc;
        } else if (tid == 128) {
            int acc = 0;
            for (int w = 0; w < 8; ++w) { grpOff[3][w] = acc; acc += waveCnt[3][w]; }
            grpOff[3][8] = acc;
        }
        __syncthreads();                                   // sync #2

        const int nIn   = grpOff[1][8];
        const int n0    = grpOff[2][8];
        const int n1Cur = grpOff[3][8];

        // order-preserving scatter (ascending index within each list)
        if (f_inA) inIdx[grpOff[0][wave] + __popcll(mAm & lt)] = tid;
        if (f_inB) inIdx[grpOff[1][wave] + __popcll(mBm & lt)] = e2;
        if (f0)    l0Idx[grpOff[2][wave] + __popcll(m0m & lt)] = tid;
        if (f1)    l1Cur[grpOff[3][wave] + __popcll(m1m & lt)] = tid;
        __syncthreads();                                   // sync #3

        // ---- cur0 (einsum engine): residue accumulators, uniform switch ----
        float e0 = 0.f, e1 = 0.f, e2f = 0.f, e3 = 0.f;
        for (int k = 0; k < nIn; ++k) {
            int   idx = inIdx[k];
            float w   = W0T[idx * H_SIZE + tid];           // coalesced row
            switch (idx & 3) {
                case 0: e0  = __fadd_rn(e0,  w); break;
                case 1: e1  = __fadd_rn(e1,  w); break;
                case 2: e2f = __fadd_rn(e2f, w); break;
                default: e3 = __fadd_rn(e3,  w); break;
            }
        }
        float cur0 = __fadd_rn(__fadd_rn(e0, e1), __fadd_rn(e2f, e3));

        // ---- cur1 (BLAS engine): two ascending sequential chains ----
        float a1 = 0.f;
        #pragma unroll 4
        for (int k = 0; k < n0; ++k)
            a1 = __fadd_rn(a1, W1T[l0Idx[k] * H_SIZE + tid]);
        float ar = 0.f;
        #pragma unroll 4
        for (int k = 0; k < n1Prev; ++k)
            ar = __fadd_rn(ar, WrecT[l1Prev[k] * H_SIZE + tid]);
        float cur1 = __fadd_rn(a1, ar);

        // ---- LIF updates: rn mul-then-add, reference order ----
        float ns0 = __fadd_rn(__fmul_rn(ALPHA, s0), cur0);
        float nm0 = __fmul_rn(__fadd_rn(__fmul_rn(BETA, m0), s0), 1.0f - (float)f0);
        float ns1 = __fadd_rn(__fmul_rn(ALPHA, s1), cur1);
        float nm1 = __fmul_rn(__fadd_rn(__fmul_rn(BETA, m1), s1), 1.0f - (float)f1);
        s0 = ns0; m0 = nm0; s1 = ns1; m1 = nm1;
        c0 += f0; c1 += f1;

        // ---- readout: h2 (einsum engine over l1Cur), rn filter ----
        if (tid < O_SIZE) {
            float g0 = 0.f, g1 = 0.f, g2 = 0.f, g3 = 0.f;
            for (int k = 0; k < n1Cur; ++k) {
                int   idx = l1Cur[k];
                float w   = WoutT[idx * O_SIZE + tid];
                switch (idx & 3) {
                    case 0: g0 = __fadd_rn(g0, w); break;
                    case 1: g1 = __fadd_rn(g1, w); break;
                    case 2: g2 = __fadd_rn(g2, w); break;
                    default: g3 = __fadd_rn(g3, w); break;
                }
            }
            float h2 = __fadd_rn(__fadd_rn(g0, g1), __fadd_rn(g2, g3));

            float nflt = __fadd_rn(__fmul_rn(ALPHA, flt), h2);
            float nout = __fadd_rn(__fmul_rn(BETA, outv), flt);  // OLD flt
            flt = nflt; outv = nout;
            out[((size_t)b * (T_STEPS + 1) + (t + 1)) * O_SIZE + tid] = __fadd_rn(nout, bo);
        }

        // rotate spk1 lists (next iter's scatter is fenced by sync #1/#2)
        int* tmp = l1Prev; l1Prev = l1Cur; l1Cur = tmp;
        n1Prev = n1Cur;
    }

    atomicAdd(&gcnt0[tid], c0);
    atomicAdd(&gcnt1[tid], c1);
}

// ---------------- reg loss ----------------
__global__ void reg_kernel(const int* __restrict__ g0,
                           const int* __restrict__ g1,
                           float* __restrict__ out_reg) {
    int tid = threadIdx.x;     // 512 threads
    double v0 = (double)g0[tid], v1 = (double)g1[tid];
    double tot = v0 + v1;
    double sq  = v0 * v0 + v1 * v1;
    for (int off = 32; off; off >>= 1) {
        tot += __shfl_down(tot, off, 64);
        sq  += __shfl_down(sq,  off, 64);
    }
    __shared__ double stot[8], ssq[8];
    if ((tid & 63) == 0) { stot[tid >> 6] = tot; ssq[tid >> 6] = sq; }
    __syncthreads();
    if (tid == 0) {
        double Tt = 0.0, Sq = 0.0;
        for (int w = 0; w < 8; ++w) { Tt += stot[w]; Sq += ssq[w]; }
        // l1 terms: REG * (tot / (T*B*H));  l2 terms: REG * (sq / H)
        double reg = REG * (Tt / 26214400.0 + Sq / 512.0);
        *out_reg = (float)reg;
    }
}

extern "C" void kernel_launch(void* const* d_in, const int* in_sizes, int n_in,
                              void* d_out, int out_size, void* d_ws, size_t ws_size,
                              hipStream_t stream) {
    const float* spikes = (const float*)d_in[0];   // (512,100,700)
    const float* W0     = (const float*)d_in[1];   // (512,700)
    const float* W1     = (const float*)d_in[2];   // (512,512)
    const float* Wrec   = (const float*)d_in[3];   // (512,512)
    const float* Wout   = (const float*)d_in[4];   // (20,512)
    const float* bout   = (const float*)d_in[5];   // (20,)
    float* out = (float*)d_out;

    float* W0T   = (float*)d_ws;                       // 700*512 f32
    float* W1T   = W0T   + (size_t)I_SIZE * H_SIZE;    // 512*512
    float* WrecT = W1T   + (size_t)H_SIZE * H_SIZE;    // 512*512
    float* WoutT = WrecT + (size_t)H_SIZE * H_SIZE;    // 512*20
    int*   gcnt0 = (int*)(WoutT + (size_t)H_SIZE * O_SIZE);
    int*   gcnt1 = gcnt0 + H_SIZE;

    int n;
    n = H_SIZE * I_SIZE;
    transpose_kernel<<<(n + 255) / 256, 256, 0, stream>>>(W0, W0T, H_SIZE, I_SIZE);
    n = H_SIZE * H_SIZE;
    transpose_kernel<<<(n + 255) / 256, 256, 0, stream>>>(W1, W1T, H_SIZE, H_SIZE);
    transpose_kernel<<<(n + 255) / 256, 256, 0, stream>>>(Wrec, WrecT, H_SIZE, H_SIZE);
    n = O_SIZE * H_SIZE;
    transpose_kernel<<<(n + 255) / 256, 256, 0, stream>>>(Wout, WoutT, O_SIZE, H_SIZE);

    init_counts_kernel<<<1, 1024, 0, stream>>>(gcnt0);

    snn_sparse_kernel<<<B_SIZE, H_SIZE, 0, stream>>>(spikes, W0T, W1T, WrecT, WoutT,
                                                     bout, out, gcnt0, gcnt1);

    reg_kernel<<<1, H_SIZE, 0, stream>>>(gcnt0, gcnt1,
                                         out + (size_t)B_SIZE * (T_STEPS + 1) * O_SIZE);
}

// Round 9
// 1137.013 us; speedup vs baseline: 15.4013x; 2.4077x over previous
//
#include <hip/hip_runtime.h>

#define T_STEPS 100
#define B_SIZE  512
#define I_SIZE  700
#define H_SIZE  512
#define O_SIZE  20

#define ALPHA 0.8187307530779818f   // exp(-0.001/0.005) rounded to f32
#define BETA  0.9048374180359595f   // exp(-0.001/0.010) rounded to f32
#define REG   1e-7

__device__ __forceinline__ int rfl(int x) { return __builtin_amdgcn_readfirstlane(x); }

// ---- sequential ascending chain (BLAS sgemm semantics), 8-deep batched ----
__device__ __forceinline__ float seq_gather(const int* __restrict__ idxs, int n,
                                            const float* __restrict__ W, int tid) {
    float a = 0.f;
    int k = 0;
    for (; k + 8 <= n; k += 8) {
        int i0 = rfl(idxs[k+0]), i1 = rfl(idxs[k+1]);
        int i2 = rfl(idxs[k+2]), i3 = rfl(idxs[k+3]);
        int i4 = rfl(idxs[k+4]), i5 = rfl(idxs[k+5]);
        int i6 = rfl(idxs[k+6]), i7 = rfl(idxs[k+7]);
        float w0 = W[(size_t)i0 * H_SIZE + tid];
        float w1 = W[(size_t)i1 * H_SIZE + tid];
        float w2 = W[(size_t)i2 * H_SIZE + tid];
        float w3 = W[(size_t)i3 * H_SIZE + tid];
        float w4 = W[(size_t)i4 * H_SIZE + tid];
        float w5 = W[(size_t)i5 * H_SIZE + tid];
        float w6 = W[(size_t)i6 * H_SIZE + tid];
        float w7 = W[(size_t)i7 * H_SIZE + tid];
        a = __fadd_rn(a, w0); a = __fadd_rn(a, w1);
        a = __fadd_rn(a, w2); a = __fadd_rn(a, w3);
        a = __fadd_rn(a, w4); a = __fadd_rn(a, w5);
        a = __fadd_rn(a, w6); a = __fadd_rn(a, w7);
    }
    for (; k < n; ++k) {
        int i = rfl(idxs[k]);
        a = __fadd_rn(a, W[(size_t)i * H_SIZE + tid]);
    }
    return a;
}

#define RES_ADD(ii, ww)                                              \
    switch ((ii) & 3) {                                              \
        case 0:  e0 = __fadd_rn(e0, (ww)); break;                    \
        case 1:  e1 = __fadd_rn(e1, (ww)); break;                    \
        case 2:  e2 = __fadd_rn(e2, (ww)); break;                    \
        default: e3 = __fadd_rn(e3, (ww)); break;                    \
    }

// ---- einsum (numpy SSE) semantics: mod-4 residue lanes, (L0+L1)+(L2+L3) ----
__device__ __forceinline__ float einsum_gather(const int* __restrict__ idxs, int n,
                                               const float* __restrict__ W, int tid) {
    float e0 = 0.f, e1 = 0.f, e2 = 0.f, e3 = 0.f;
    int k = 0;
    for (; k + 4 <= n; k += 4) {
        int i0 = rfl(idxs[k+0]), i1 = rfl(idxs[k+1]);
        int i2 = rfl(idxs[k+2]), i3 = rfl(idxs[k+3]);
        float w0 = W[(size_t)i0 * H_SIZE + tid];
        float w1 = W[(size_t)i1 * H_SIZE + tid];
        float w2 = W[(size_t)i2 * H_SIZE + tid];
        float w3 = W[(size_t)i3 * H_SIZE + tid];
        RES_ADD(i0, w0); RES_ADD(i1, w1); RES_ADD(i2, w2); RES_ADD(i3, w3);
    }
    for (; k < n; ++k) {
        int i = rfl(idxs[k]);
        float w = W[(size_t)i * H_SIZE + tid];
        RES_ADD(i, w);
    }
    return __fadd_rn(__fadd_rn(e0, e1), __fadd_rn(e2, e3));
}

// ---------------- transpose: out[c*R + r] = in[r*C + c] ----------------
__global__ void transpose_kernel(const float* __restrict__ in,
                                 float* __restrict__ out, int R, int C) {
    int idx = blockIdx.x * blockDim.x + threadIdx.x;
    if (idx < R * C) {
        int r = idx / C, c = idx % C;
        out[c * R + r] = in[r * C + c];
    }
}

// ---------------- zero the spike-count accumulators ----------------
__global__ void init_counts_kernel(int* __restrict__ g) {
    int tid = threadIdx.x;
    if (tid < 2 * H_SIZE) g[tid] = 0;
}

// ---------------- main SNN kernel: one block per batch element ----------------
// Bitwise-identical arithmetic to the verified R7/R8 engine model:
//   einsum dots: mod-4 residue chains, ascending, (L0+L1)+(L2+L3);
//   BLAS dots: ascending sequential chains, two results added f32;
//   states/filter: rn mul-then-add in reference order.
// Perf structure: 2 barriers/step, SGPR-addressed batched gathers, deferred
// parallel readout from stored per-step spike masks.
__global__ __launch_bounds__(512, 1)
void snn_sparse2_kernel(const float* __restrict__ spikes,   // (B,T,I)
                        const float* __restrict__ W0T,      // (I,H)
                        const float* __restrict__ W1T,      // (H,H)
                        const float* __restrict__ WrecT,    // (H,H)
                        const float* __restrict__ WoutT,    // (H,O)
                        const float* __restrict__ bout,     // (O)
                        float* __restrict__ out,            // (B,T+1,O)
                        int* __restrict__ gcnt0,            // (H)
                        int* __restrict__ gcnt1)            // (H)
{
    const int tid  = threadIdx.x;          // h index
    const int b    = blockIdx.x;
    const int lane = tid & 63;
    const int wave = tid >> 6;
    const unsigned long long lt = (1ULL << lane) - 1ULL;

    __shared__ int  inIdx[I_SIZE];
    __shared__ int  l0Idx[H_SIZE];
    __shared__ int  l1A[H_SIZE];
    __shared__ int  l1B[H_SIZE];
    __shared__ int4 waveCnt4[8];
    __shared__ unsigned long long maskT[T_STEPS][8];   // layer-1 ballots per step
    __shared__ float h2buf[T_STEPS][O_SIZE];

    float m0 = 0.f, s0 = 0.f, m1 = 0.f, s1 = 0.f;
    int   c0 = 0, c1 = 0;

    int* l1Prev = l1A;
    int* l1Cur  = l1B;
    int  n1Prev = 0;

    const float* srow = spikes + (size_t)b * T_STEPS * I_SIZE;

    // prefetch step-0 spikes
    float spA = srow[tid];
    float spB = (tid < I_SIZE - H_SIZE) ? srow[H_SIZE + tid] : 0.f;

    for (int t = 0; t < T_STEPS; ++t) {
        int f_inA = (spA != 0.f);
        int f_inB = (spB != 0.f);
        int f0    = ((m0 - 1.0f) > 0.0f);
        int f1    = ((m1 - 1.0f) > 0.0f);

        unsigned long long mAm = __ballot(f_inA);
        unsigned long long mBm = __ballot(f_inB);
        unsigned long long m0m = __ballot(f0);
        unsigned long long m1m = __ballot(f1);
        if (lane == 0) {
            waveCnt4[wave] = make_int4(__popcll(mAm), __popcll(mBm),
                                       __popcll(m0m), __popcll(m1m));
            maskT[t][wave] = m1m;
        }
        __syncthreads();                                   // sync A

        // redundant per-thread prefix over the 8 per-wave counts
        int sumA = 0, sumB = 0, sum0 = 0, sum1 = 0;
        int offA = 0, offB = 0, off0 = 0, off1 = 0;
        #pragma unroll
        for (int w = 0; w < 8; ++w) {
            int4 c = waveCnt4[w];
            if (w == wave) { offA = sumA; offB = sumB; off0 = sum0; off1 = sum1; }
            sumA += c.x; sumB += c.y; sum0 += c.z; sum1 += c.w;
        }
        const int nIn   = sumA + sumB;
        const int n0    = sum0;
        const int n1Cur = sum1;

        // order-preserving scatter (ascending index within each list)
        if (f_inA) inIdx[offA + __popcll(mAm & lt)]        = tid;
        if (f_inB) inIdx[sumA + offB + __popcll(mBm & lt)] = 512 + tid;
        if (f0)    l0Idx[off0 + __popcll(m0m & lt)]        = tid;
        if (f1)    l1Cur[off1 + __popcll(m1m & lt)]        = tid;
        __syncthreads();                                   // sync B

        // prefetch next step's spikes (consumed at next iteration's flags)
        if (t + 1 < T_STEPS) {
            spA = srow[(t + 1) * I_SIZE + tid];
            spB = (tid < I_SIZE - H_SIZE) ? srow[(t + 1) * I_SIZE + H_SIZE + tid] : 0.f;
        }

        // ---- gathers ----
        float cur0 = einsum_gather(inIdx, nIn, W0T, tid);
        float a1   = seq_gather(l0Idx, n0, W1T, tid);
        float ar   = seq_gather(l1Prev, n1Prev, WrecT, tid);
        float cur1 = __fadd_rn(a1, ar);

        // ---- LIF updates: rn mul-then-add, reference order ----
        float ns0 = __fadd_rn(__fmul_rn(ALPHA, s0), cur0);
        float nm0 = __fmul_rn(__fadd_rn(__fmul_rn(BETA, m0), s0), 1.0f - (float)f0);
        float ns1 = __fadd_rn(__fmul_rn(ALPHA, s1), cur1);
        float nm1 = __fmul_rn(__fadd_rn(__fmul_rn(BETA, m1), s1), 1.0f - (float)f1);
        s0 = ns0; m0 = nm0; s1 = ns1; m1 = nm1;
        c0 += f0; c1 += f1;

        // rotate spk1 lists (writes to the new l1Cur happen after next sync A)
        int* tmp = l1Prev; l1Prev = l1Cur; l1Cur = tmp;
        n1Prev = n1Cur;
    }

    atomicAdd(&gcnt0[tid], c0);
    atomicAdd(&gcnt1[tid], c1);
    __syncthreads();   // all maskT writes complete

    // ---- phase 2: h2[t][o] for all t in parallel (einsum semantics) ----
    {
        int grp = tid / O_SIZE;        // 0..25 (threads 500..511 idle)
        int o   = tid % O_SIZE;
        if (grp < 25) {
            for (int tt = grp; tt < T_STEPS; tt += 25) {
                float e0 = 0.f, e1 = 0.f, e2 = 0.f, e3 = 0.f;
                #pragma unroll
                for (int w = 0; w < 8; ++w) {
                    unsigned long long m = maskT[tt][w];
                    int base = w * 64;
                    while (m) {
                        int idx = base + (int)__builtin_ctzll(m);
                        m &= m - 1;
                        float wv = WoutT[(size_t)idx * O_SIZE + o];
                        RES_ADD(idx, wv);
                    }
                }
                h2buf[tt][o] = __fadd_rn(__fadd_rn(e0, e1), __fadd_rn(e2, e3));
            }
        }
    }
    __syncthreads();

    // ---- phase 3: double-exp filter recurrence (20 threads) ----
    if (tid < O_SIZE) {
        float bo  = bout[tid];
        float flt = 0.f, outv = 0.f;
        out[((size_t)b * (T_STEPS + 1)) * O_SIZE + tid] = bo;   // t = 0 row
        for (int tt = 0; tt < T_STEPS; ++tt) {
            float h2   = h2buf[tt][tid];
            float nflt = __fadd_rn(__fmul_rn(ALPHA, flt), h2);
            float nout = __fadd_rn(__fmul_rn(BETA, outv), flt);  // OLD flt
            flt = nflt; outv = nout;
            out[((size_t)b * (T_STEPS + 1) + (tt + 1)) * O_SIZE + tid] = __fadd_rn(nout, bo);
        }
    }
}

// ---------------- reg loss ----------------
__global__ void reg_kernel(const int* __restrict__ g0,
                           const int* __restrict__ g1,
                           float* __restrict__ out_reg) {
    int tid = threadIdx.x;     // 512 threads
    double v0 = (double)g0[tid], v1 = (double)g1[tid];
    double tot = v0 + v1;
    double sq  = v0 * v0 + v1 * v1;
    for (int off = 32; off; off >>= 1) {
        tot += __shfl_down(tot, off, 64);
        sq  += __shfl_down(sq,  off, 64);
    }
    __shared__ double stot[8], ssq[8];
    if ((tid & 63) == 0) { stot[tid >> 6] = tot; ssq[tid >> 6] = sq; }
    __syncthreads();
    if (tid == 0) {
        double Tt = 0.0, Sq = 0.0;
        for (int w = 0; w < 8; ++w) { Tt += stot[w]; Sq += ssq[w]; }
        // l1 terms: REG * (tot / (T*B*H));  l2 terms: REG * (sq / H)
        double reg = REG * (Tt / 26214400.0 + Sq / 512.0);
        *out_reg = (float)reg;
    }
}

extern "C" void kernel_launch(void* const* d_in, const int* in_sizes, int n_in,
                              void* d_out, int out_size, void* d_ws, size_t ws_size,
                              hipStream_t stream) {
    const float* spikes = (const float*)d_in[0];   // (512,100,700)
    const float* W0     = (const float*)d_in[1];   // (512,700)
    const float* W1     = (const float*)d_in[2];   // (512,512)
    const float* Wrec   = (const float*)d_in[3];   // (512,512)
    const float* Wout   = (const float*)d_in[4];   // (20,512)
    const float* bout   = (const float*)d_in[5];   // (20,)
    float* out = (float*)d_out;

    float* W0T   = (float*)d_ws;                       // 700*512 f32
    float* W1T   = W0T   + (size_t)I_SIZE * H_SIZE;    // 512*512
    float* WrecT = W1T   + (size_t)H_SIZE * H_SIZE;    // 512*512
    float* WoutT = WrecT + (size_t)H_SIZE * H_SIZE;    // 512*20
    int*   gcnt0 = (int*)(WoutT + (size_t)H_SIZE * O_SIZE);
    int*   gcnt1 = gcnt0 + H_SIZE;

    int n;
    n = H_SIZE * I_SIZE;
    transpose_kernel<<<(n + 255) / 256, 256, 0, stream>>>(W0, W0T, H_SIZE, I_SIZE);
    n = H_SIZE * H_SIZE;
    transpose_kernel<<<(n + 255) / 256, 256, 0, stream>>>(W1, W1T, H_SIZE, H_SIZE);
    transpose_kernel<<<(n + 255) / 256, 256, 0, stream>>>(Wrec, WrecT, H_SIZE, H_SIZE);
    n = O_SIZE * H_SIZE;
    transpose_kernel<<<(n + 255) / 256, 256, 0, stream>>>(Wout, WoutT, O_SIZE, H_SIZE);

    init_counts_kernel<<<1, 1024, 0, stream>>>(gcnt0);

    snn_sparse2_kernel<<<B_SIZE, H_SIZE, 0, stream>>>(spikes, W0T, W1T, WrecT, WoutT,
                                                      bout, out, gcnt0, gcnt1);

    reg_kernel<<<1, H_SIZE, 0, stream>>>(gcnt0, gcnt1,
                                         out + (size_t)B_SIZE * (T_STEPS + 1) * O_SIZE);
}